// Round 1
// baseline (474.436 us; speedup 1.0000x reference)
//
#include <hip/hip_runtime.h>
#include <hip/hip_bf16.h>

// BitLevelMapper: bits [B,16] int32 {0,1} (mem index j holds bit 15-j),
// tables [16, 32768] float32 {0,1}. For bit i: addr = value of bits 0..i-1,
// flip = tables[i][addr], out bit i = bit i ^ flip. Output float32, same
// reversed layout as input.
//
// Key insight: row i of tables only ever addressed at addr < 2^i, so the
// live table is sum_i 2^i = 65535 bits ~= 8 KB packed -> LDS.

#define PACK_WORDS 2048   // 65536 bits (65535 used), 8 KB

__global__ void pack_tables_kernel(const float* __restrict__ tables,
                                   unsigned* __restrict__ packed) {
    int w = blockIdx.x * blockDim.x + threadIdx.x;
    if (w >= PACK_WORDS) return;
    unsigned word = 0u;
    #pragma unroll
    for (int b = 0; b < 32; ++b) {
        int g = w * 32 + b;            // global bit index
        if (g < 65535) {
            int i = 31 - __clz(g + 1);          // row: (2^i - 1) <= g < (2^{i+1} - 1)
            int a = g - ((1 << i) - 1);         // address within row
            if (tables[i * 32768 + a] != 0.0f) word |= (1u << b);
        }
    }
    packed[w] = word;
}

__global__ __launch_bounds__(256) void
blm_kernel(const int* __restrict__ bits, const unsigned* __restrict__ packed,
           float* __restrict__ out, int nrows) {
    __shared__ unsigned tab[PACK_WORDS];
    for (int k = threadIdx.x; k < PACK_WORDS; k += blockDim.x)
        tab[k] = packed[k];
    __syncthreads();

    int stride = gridDim.x * blockDim.x;
    for (int r = blockIdx.x * blockDim.x + threadIdx.x; r < nrows; r += stride) {
        const int4* bp = (const int4*)(bits + (size_t)r * 16);
        int4 m0 = bp[0];
        int4 m1 = bp[1];
        int4 m2 = bp[2];
        int4 m3 = bp[3];
        int mem[16] = {m0.x, m0.y, m0.z, m0.w,
                       m1.x, m1.y, m1.z, m1.w,
                       m2.x, m2.y, m2.z, m2.w,
                       m3.x, m3.y, m3.z, m3.w};
        // v bit k = input bit k (LSB); mem[j] holds bit 15-j
        unsigned v = 0u;
        #pragma unroll
        for (int j = 0; j < 16; ++j)
            v |= ((unsigned)mem[j]) << (15 - j);

        float o[16];
        #pragma unroll
        for (int i = 0; i < 16; ++i) {
            unsigned mask   = (1u << i) - 1u;
            unsigned bitidx = mask + (v & mask);        // (2^i - 1) + addr
            unsigned fl     = (tab[bitidx >> 5] >> (bitidx & 31u)) & 1u;
            unsigned ob     = ((v >> i) & 1u) ^ fl;
            o[15 - i] = (float)ob;                       // back to memory order
        }

        float4* op = (float4*)(out + (size_t)r * 16);
        op[0] = make_float4(o[0],  o[1],  o[2],  o[3]);
        op[1] = make_float4(o[4],  o[5],  o[6],  o[7]);
        op[2] = make_float4(o[8],  o[9],  o[10], o[11]);
        op[3] = make_float4(o[12], o[13], o[14], o[15]);
    }
}

extern "C" void kernel_launch(void* const* d_in, const int* in_sizes, int n_in,
                              void* d_out, int out_size, void* d_ws, size_t ws_size,
                              hipStream_t stream) {
    const int*   bits   = (const int*)d_in[0];
    const float* tables = (const float*)d_in[1];
    float*       out    = (float*)d_out;
    unsigned*    packed = (unsigned*)d_ws;   // 8 KB used

    int nrows = in_sizes[0] / 16;            // 4194304

    pack_tables_kernel<<<(PACK_WORDS + 255) / 256, 256, 0, stream>>>(tables, packed);

    int block = 256;
    int grid  = 4096;                        // 1M threads, 4 rows/thread, grid-stride
    blm_kernel<<<grid, block, 0, stream>>>(bits, packed, out, nrows);
}

// Round 2
// 434.868 us; speedup vs baseline: 1.0910x; 1.0910x over previous
//
#include <hip/hip_runtime.h>
#include <hip/hip_bf16.h>

// BitLevelMapper: bits [B,16] int32 {0,1} (mem index j holds value bit 15-j),
// tables [16, 32768] float32 {0,1}. For bit i: addr = value of bits 0..i-1,
// flip = tables[i][addr], out bit i = bit i ^ flip. Output float32, reversed
// layout like input.
//
// Live table = sum_i 2^i = 65535 bits ~= 8 KB packed -> LDS.
// R1: fully lane-contiguous global IO (16 B/lane); rows assembled/distributed
// via wave shuffles instead of 64 B-strided per-thread access.

#define PACK_WORDS 2048   // 65536 bits (65535 used), 8 KB

__global__ __launch_bounds__(256) void
pack_tables_kernel(const float* __restrict__ tables, unsigned* __restrict__ packed) {
    int g = blockIdx.x * blockDim.x + threadIdx.x;   // global bit index
    bool val = false;
    if (g < 65535) {
        int i = 31 - __clz(g + 1);            // row: (2^i - 1) <= g < (2^{i+1} - 1)
        int a = g - ((1 << i) - 1);           // address within row
        val = tables[i * 32768 + a] != 0.0f;
    }
    unsigned long long m = __ballot(val);
    if ((threadIdx.x & 63) == 0) {            // one writer per wave, 2 words
        packed[(g >> 5)]     = (unsigned)m;
        packed[(g >> 5) + 1] = (unsigned)(m >> 32);
    }
}

__global__ __launch_bounds__(256) void
blm_kernel(const int4* __restrict__ bits4, const unsigned* __restrict__ packed,
           float4* __restrict__ out4, int nrows) {
    __shared__ unsigned tab[PACK_WORDS];
    for (int k = threadIdx.x; k < PACK_WORDS; k += 256)
        tab[k] = packed[k];
    __syncthreads();

    const int lane    = threadIdx.x & 63;
    const int wave    = (blockIdx.x * 256 + threadIdx.x) >> 6;
    const int nwaves  = (gridDim.x * 256) >> 6;
    const int nchunks = nrows >> 6;           // 64 rows per wave-chunk

    for (int c = wave; c < nchunks; c += nwaves) {
        const size_t base = (size_t)c * 256;  // int4 index of chunk start

        // Coalesced loads: round j, lane t holds row j*16+(t>>2), quarter t&3.
        int4 m0 = bits4[base +   0 + lane];
        int4 m1 = bits4[base +  64 + lane];
        int4 m2 = bits4[base + 128 + lane];
        int4 m3 = bits4[base + 192 + lane];

        // int4 (mem pos 4q..4q+3) -> nibble, bit3 = value bit 15-4q
        unsigned n0 = (unsigned)((m0.x << 3) | (m0.y << 2) | (m0.z << 1) | m0.w);
        unsigned n1 = (unsigned)((m1.x << 3) | (m1.y << 2) | (m1.z << 1) | m1.w);
        unsigned n2 = (unsigned)((m2.x << 3) | (m2.y << 2) | (m2.z << 1) | m2.w);
        unsigned n3 = (unsigned)((m3.x << 3) | (m3.y << 2) | (m3.z << 1) | m3.w);
        unsigned pk = n0 | (n1 << 4) | (n2 << 8) | (n3 << 12);  // shift 4j <-> round j

        // Gather: row L=lane needs quarter q from lane (L&15)*4+q, round L>>4.
        const int hi   = lane >> 4;           // round holding my row
        const int bsrc = (lane & 15) << 2;
        unsigned v = 0;
        #pragma unroll
        for (int q = 0; q < 4; ++q) {
            unsigned x  = (unsigned)__shfl((int)pk, bsrc + q, 64);
            unsigned nb = (x >> (hi * 4)) & 0xFu;
            v |= nb << (12 - 4 * q);          // quarter q = value bits 15-4q..12-4q
        }

        // 16 independent LDS bit lookups; r16 bit i = output value bit i.
        unsigned r16 = 0;
        #pragma unroll
        for (int i = 0; i < 16; ++i) {
            unsigned mask = (1u << i) - 1u;
            unsigned bidx = mask + (v & mask);            // (2^i-1) + addr
            unsigned fl   = (tab[bidx >> 5] >> (bidx & 31u));
            r16 |= (((v >> i) ^ fl) & 1u) << i;
        }

        // Scatter + coalesced stores: round j, lane t stores row j*16+(t>>2),
        // quarter t&3 (float4 = value bits 15-4q..12-4q).
        #pragma unroll
        for (int j = 0; j < 4; ++j) {
            unsigned y = (unsigned)__shfl((int)r16, (j << 4) + (lane >> 2), 64);
            int q4 = (lane & 3) << 2;
            float4 f;
            f.x = (float)((y >> (15 - q4)) & 1u);
            f.y = (float)((y >> (14 - q4)) & 1u);
            f.z = (float)((y >> (13 - q4)) & 1u);
            f.w = (float)((y >> (12 - q4)) & 1u);
            out4[base + j * 64 + lane] = f;
        }
    }
}

extern "C" void kernel_launch(void* const* d_in, const int* in_sizes, int n_in,
                              void* d_out, int out_size, void* d_ws, size_t ws_size,
                              hipStream_t stream) {
    const int*   bits   = (const int*)d_in[0];
    const float* tables = (const float*)d_in[1];
    float*       out    = (float*)d_out;
    unsigned*    packed = (unsigned*)d_ws;   // 8 KB used

    int nrows = in_sizes[0] / 16;            // 4194304

    pack_tables_kernel<<<65536 / 256, 256, 0, stream>>>(tables, packed);

    blm_kernel<<<8192, 256, 0, stream>>>((const int4*)bits, packed,
                                         (float4*)out, nrows);
}